// Round 10
// baseline (166.760 us; speedup 1.0000x reference)
//
#include <hip/hip_runtime.h>
#include <hip/hip_bf16.h>

#define N_NODES 50000
#define N_EDGES 800000
#define D_IN 96
#define D_OUT 128
#define CAP 64              // deg ~ Poisson(16); P(deg>=64) ~ e^-41 -> no drops

// XCD-sliced fill (R5): 8 slices x 6250 nodes; block group g = blockIdx&7
// lands on XCD g (round-robin heuristic); bucket/cursor lines for a slice are
// written from ONE XCD -> merge in its L2 instead of churning HBM.
#define SLICES 8
#define NODES_PER_SLICE 6250
#define GROUP_BLOCKS 256
#define FILL_BLOCKS (SLICES * GROUP_BLOCKS)         // 2048
#define EDGES_PER_BLOCK 3125                        // 3125*256 = 800000 exactly

#define CONV_THREADS (N_NODES * 12)                 // 600000 (one per 8-elem chunk)
#define CONV_BLOCKS ((CONV_THREADS + 255) / 256)    // 2344
#define WCONV_BLOCKS 12                             // 128*24 = 3072 tasks
#define ZROW_BLOCKS 1                               // zero bf16 row @ index 0xFFFF

// fused agg+gemm: 64 nodes/block, 768 threads (12 waves):
//   phase A: ONE task per thread (64 nodes x 12 chunks = 768), bf16 gathers
//   phase B: waves 0..3 run the 4 x 16-node MFMA tiles; waves 4..11 exit
#define NPB 64
#define AG_BLOCKS ((N_NODES + NPB - 1) / NPB)       // 782
#define AH_PITCH 104        // u16/row (96 + 8 pad); 208 B rows, b128-aligned

// ws layout (aligned sections). xh spans 65536 rows so id 0xFFFF hits a
// dedicated zero row (unguarded pad-gathers).
#define WS_BUCKET 200192
#define WS_XH     (WS_BUCKET + 6400000)             // 6600192
#define WS_WFRAG  (WS_XH + 65536 * 192)             // 6600192 + 12582912

typedef unsigned short u16;
typedef __attribute__((ext_vector_type(8))) short short8;   // 8 x bf16 (4 VGPRs)
typedef __attribute__((ext_vector_type(4))) float f32x4;

__device__ __forceinline__ u16 f2bf(float f) {
    unsigned u = __float_as_uint(f);
    unsigned r = (u + 0x7FFFu + ((u >> 16) & 1u)) >> 16;   // RNE
    return (u16)r;
}

// ---------------------------------------------------------------------------
// K1: heterogeneous grid.
//   [0, FILL_BLOCKS): XCD-sliced edge binning.
//   [+CONV_BLOCKS): xh = bf16(x), row-major [n][96].
//   [+WCONV_BLOCKS): Wfrag = bf16 B-fragment layout of [Wl|Wr].
//   [+ZROW_BLOCKS): zero the bf16 row at index 0xFFFF (gather-pad target).
// fill is store-transaction bound with idle pipes; conversions ride free.
// ---------------------------------------------------------------------------
__global__ __launch_bounds__(256) void sage_fill_conv(
    const int* __restrict__ src,
    const int* __restrict__ dst,
    const float* __restrict__ x,
    const float* __restrict__ Wl,
    const float* __restrict__ Wr,
    int* __restrict__ cursor,
    u16* __restrict__ bucket,
    u16* __restrict__ xh,
    u16* __restrict__ Wfrag)
{
    const int b = blockIdx.x;
    if (b < FILL_BLOCKS) {
        const int slice = b & 7;
        const int gb = b >> 3;
        const int lo = slice * NODES_PER_SLICE;
        const int hi = lo + NODES_PER_SLICE;
        const int e0 = gb * EDGES_PER_BLOCK;
        int e1 = e0 + EDGES_PER_BLOCK;
        if (e1 > N_EDGES) e1 = N_EDGES;
        for (int e = e0 + (int)threadIdx.x; e < e1; e += 256) {
            int d = dst[e];
            int s = src[e];
            if (d >= lo && d < hi) {
                int pos = atomicAdd(&cursor[d], 1);
                if (pos < CAP) bucket[(size_t)d * CAP + pos] = (u16)s;
            }
        }
    } else if (b < FILL_BLOCKS + CONV_BLOCKS) {
        unsigned t = (unsigned)(b - FILL_BLOCKS) * 256u + threadIdx.x;
        if (t >= (unsigned)CONV_THREADS) return;
        unsigned n = t / 12u;
        unsigned c8 = t - n * 12u;
        const float* p = x + (size_t)n * D_IN + c8 * 8u;
        short8 hv;
#pragma unroll
        for (int i = 0; i < 8; i++) hv[i] = (short)f2bf(p[i]);
        *(short8*)(xh + (size_t)n * D_IN + c8 * 8u) = hv;
    } else if (b < FILL_BLOCKS + CONV_BLOCKS + WCONV_BLOCKS) {
        // W -> bf16 B-fragments: 128 j x 24 chunks (12 Wl + 12 Wr)
        int idx = (b - FILL_BLOCKS - CONV_BLOCKS) * 256 + (int)threadIdx.x; // <3072
        int j = idx / 24;
        int c8 = idx - j * 24;
        int kc = c8 >> 2;
        int quad = c8 & 3;
        const float* wsrc = (c8 < 12) ? (Wl + (size_t)j * D_IN + c8 * 8)
                                      : (Wr + (size_t)j * D_IN + (c8 - 12) * 8);
        int jt = j >> 4;
        int col = j & 15;
        short8 v;
#pragma unroll
        for (int i = 0; i < 8; i++) v[i] = (short)f2bf(wsrc[i]);
        *(short8*)(Wfrag + (((jt * 6 + kc) * 64) + col + 16 * quad) * 8) = v;
    } else {
        // zero row @ 0xFFFF: pad-gathers land here and add 0.0 (192 B = 48 u32)
        if (threadIdx.x < 48)
            ((unsigned*)(xh + 65535u * (unsigned)D_IN))[threadIdx.x] = 0u;
    }
}

// ---------------------------------------------------------------------------
// K2 (fused): bf16 mean-aggregation into LDS Ah, then MFMA GEMM.
// 768 threads = 12 waves; ~24 waves/CU resident in phase A.
// Phase A: ONE task per thread: (node m:64) x (chunk c12:12 of 8 bf16).
//   Bucket prefilled with 0xFFFF -> tail gathers hit the zero xh row: NO
//   predication;每 burst = 8 unguarded 16B gathers with the NEXT burst's
//   8 indices prefetched (software pipeline). Decode = 1 shift/elem.
// Phase B: waves 0..3 run the 4 x 16-node MFMA tiles (R7-verified layout);
//   waves 4..11 return after the barrier.
// ---------------------------------------------------------------------------
__global__ __launch_bounds__(768, 6) void sage_agg_gemm(
    const u16* __restrict__ xh,
    const int* __restrict__ cursor,
    const u16* __restrict__ bucket,
    const u16* __restrict__ Wfrag,
    const float* __restrict__ bl,
    float* __restrict__ out)
{
    __shared__ u16 Ah[NPB * AH_PITCH];      // 13312 B

    const int tid = threadIdx.x;
    const int n0 = blockIdx.x * NPB;

    // ---- phase A: one (node, 16B-chunk) task per thread ----
    {
        int m = tid / 12;                    // node 0..63
        int c12 = tid - m * 12;              // 16-B chunk 0..11
        int n = n0 + m;

        float acc[8];
#pragma unroll
        for (int i = 0; i < 8; i++) acc[i] = 0.0f;
        float invd = 0.0f;

        if (n < N_NODES) {
            int deg = cursor[n];
            int degc = deg < CAP ? deg : CAP;
            const u16* brow = bucket + (size_t)n * CAP;
            const char* xb = (const char*)xh + (unsigned)c12 * 16u;

            short8 id = *(const short8*)brow;            // burst-0 indices
            for (int base = 0; base < degc; base += 8) {
                // prefetch next burst's indices (may read 16B past the row:
                // lands in the next bucket row / xh region - harmless)
                short8 idn = *(const short8*)(brow + base + 8);
                uint4 w[8];
#pragma unroll
                for (int q = 0; q < 8; q++) {
                    unsigned s = (u16)id[q];             // 0xFFFF -> zero row
                    w[q] = *(const uint4*)(xb + s * 192u);
                }
#pragma unroll
                for (int q = 0; q < 8; q++) {
                    // 8 bf16 in w[q]; decode lo = u<<16, hi = u & 0xFFFF0000
                    acc[0] += __uint_as_float(w[q].x << 16);
                    acc[1] += __uint_as_float(w[q].x & 0xFFFF0000u);
                    acc[2] += __uint_as_float(w[q].y << 16);
                    acc[3] += __uint_as_float(w[q].y & 0xFFFF0000u);
                    acc[4] += __uint_as_float(w[q].z << 16);
                    acc[5] += __uint_as_float(w[q].z & 0xFFFF0000u);
                    acc[6] += __uint_as_float(w[q].w << 16);
                    acc[7] += __uint_as_float(w[q].w & 0xFFFF0000u);
                }
                id = idn;
            }
            invd = 1.0f / fmaxf((float)deg, 1.0f);
        }

        short8 o;
#pragma unroll
        for (int i = 0; i < 8; i++) o[i] = (short)f2bf(acc[i] * invd);
        *(short8*)(Ah + m * AH_PITCH + c12 * 8) = o;
    }
    __syncthreads();

    // ---- phase B: waves 0..3 each run one 16-node MFMA tile ----
    const int wave = tid >> 6;
    if (wave >= 4) return;
    const int lane = tid & 63;
    const int m16 = lane & 15;
    const int quad = lane >> 4;
    const int tilebase = n0 + wave * 16;
    if (tilebase >= N_NODES) return;

    int nn = tilebase + m16;
    nn = nn < N_NODES ? nn : N_NODES - 1;    // clamp A-row source (store guarded)

    const u16* arow = Ah + (wave * 16 + m16) * AH_PITCH + quad * 8;
    const u16* xrow = xh + (size_t)nn * D_IN + quad * 8;
    short8 a[6];
#pragma unroll
    for (int kc = 0; kc < 3; kc++) a[kc]     = *(const short8*)(arow + kc * 32);
#pragma unroll
    for (int kc = 0; kc < 3; kc++) a[3 + kc] = *(const short8*)(xrow + kc * 32);

#pragma unroll
    for (int jt = 0; jt < 8; jt++) {
        f32x4 acc = {0.0f, 0.0f, 0.0f, 0.0f};
#pragma unroll
        for (int kc = 0; kc < 6; kc++) {
            short8 bfrag = *(const short8*)(Wfrag + ((jt * 6 + kc) * 64 + lane) * 8);
            acc = __builtin_amdgcn_mfma_f32_16x16x32_bf16(a[kc], bfrag, acc, 0, 0, 0);
        }
        const int j = jt * 16 + m16;         // col = lane&15
        const float bj = bl[j];
#pragma unroll
        for (int r = 0; r < 4; r++) {
            int row = quad * 4 + r;
            int n = tilebase + row;
            if (n < N_NODES)
                out[(size_t)n * D_OUT + j] = fmaxf(acc[r] + bj, 0.0f);
        }
    }
}

extern "C" void kernel_launch(void* const* d_in, const int* in_sizes, int n_in,
                              void* d_out, int out_size, void* d_ws, size_t ws_size,
                              hipStream_t stream) {
    const float* x   = (const float*)d_in[0];
    const int* eidx  = (const int*)d_in[1];
    const float* Wl  = (const float*)d_in[2];
    const float* bl  = (const float*)d_in[3];
    const float* Wr  = (const float*)d_in[4];
    float* out = (float*)d_out;

    const int* src = eidx;                // edge_index[0]
    const int* dst = eidx + N_EDGES;      // edge_index[1]

    char* ws = (char*)d_ws;
    int* cursor = (int*)ws;
    u16* bucket = (u16*)(ws + WS_BUCKET);
    u16* xh     = (u16*)(ws + WS_XH);
    u16* Wfrag  = (u16*)(ws + WS_WFRAG);

    hipMemsetAsync(cursor, 0, N_NODES * sizeof(int), stream);
    hipMemsetAsync(bucket, 0xFF, (size_t)N_NODES * CAP * sizeof(u16), stream);

    {
        dim3 grid(FILL_BLOCKS + CONV_BLOCKS + WCONV_BLOCKS + ZROW_BLOCKS); // 4405
        sage_fill_conv<<<grid, 256, 0, stream>>>(src, dst, x, Wl, Wr,
                                                 cursor, bucket, xh, Wfrag);
    }
    {
        dim3 grid(AG_BLOCKS);                                  // 782
        sage_agg_gemm<<<grid, 768, 0, stream>>>(xh, cursor, bucket,
                                                Wfrag, bl, out);
    }
}